// Round 2
// baseline (771.042 us; speedup 1.0000x reference)
//
#include <hip/hip_runtime.h>

#define IN_DIM 256
#define HID 64
#define HEADS 4
#define C1 256   // HID*HEADS

// ---------------------------------------------------------------------------
// CSR build: histogram of dst -> exclusive scan -> atomic fill of src lists
// ---------------------------------------------------------------------------

__global__ __launch_bounds__(256) void zero_int_kernel(int* __restrict__ p, int n) {
  int i = blockIdx.x * 256 + threadIdx.x;
  if (i < n) p[i] = 0;
}

__global__ __launch_bounds__(256) void hist_kernel(const int* __restrict__ ei,
                                                   int E, int N, int* __restrict__ counts) {
  int e = blockIdx.x * 256 + threadIdx.x;
  if (e >= E + N) return;
  int dst = (e < E) ? ei[(size_t)E + e] : (e - E);
  atomicAdd(&counts[dst], 1);
}

__global__ __launch_bounds__(1024) void scan_kernel(const int* __restrict__ counts,
                                                    int* __restrict__ indptr,
                                                    int* __restrict__ fillpos, int N) {
  __shared__ int sdata[1024];
  int tid = threadIdx.x;
  int running = 0;
  for (int base = 0; base < N; base += 1024) {
    int v = (base + tid < N) ? counts[base + tid] : 0;
    sdata[tid] = v;
    __syncthreads();
    for (int off = 1; off < 1024; off <<= 1) {
      int t = (tid >= off) ? sdata[tid - off] : 0;
      __syncthreads();
      sdata[tid] += t;
      __syncthreads();
    }
    int excl = sdata[tid] - v;
    if (base + tid < N) {
      indptr[base + tid] = running + excl;
      fillpos[base + tid] = running + excl;
    }
    int total = sdata[1023];
    __syncthreads();
    running += total;
  }
  if (tid == 0) indptr[N] = running;
}

__global__ __launch_bounds__(256) void fill_kernel(const int* __restrict__ ei, int E, int N,
                                                   int* __restrict__ fillpos, int* __restrict__ srcs) {
  int e = blockIdx.x * 256 + threadIdx.x;
  if (e >= E + N) return;
  int src, dst;
  if (e < E) { src = ei[e]; dst = ei[(size_t)E + e]; }
  else       { src = e - E; dst = e - E; }
  int pos = atomicAdd(&fillpos[dst], 1);
  srcs[pos] = src;
}

// ---------------------------------------------------------------------------
// Tiled f32 GEMM: C[M,NC] = A[M,K] @ B[K,NC]   (BM=BN=64, BK=32, 4x4 micro)
// ---------------------------------------------------------------------------

__global__ __launch_bounds__(256) void gemm_kernel(const float* __restrict__ A,
                                                   const float* __restrict__ B,
                                                   float* __restrict__ C,
                                                   int M, int NC, int K) {
  const int BM = 64, BN = 64, BK = 32, TM = 4, TN = 4;
  __shared__ float As[BK][BM + 4];
  __shared__ float Bs[BK][BN + 4];
  int bm = blockIdx.x * BM;
  int bn = blockIdx.y * BN;
  int tid = threadIdx.x;
  int tr = tid >> 4;   // 0..15
  int tc = tid & 15;   // 0..15
  float acc[TM][TN] = {};
  for (int k0 = 0; k0 < K; k0 += BK) {
    // A tile 64x32 (2048 elems, 8 per thread), stored transposed As[k][m]
    #pragma unroll
    for (int it = 0; it < (BM * BK) / 256; ++it) {
      int i = tid + it * 256;
      int r = i >> 5, c = i & 31;
      int row = bm + r;
      As[c][r] = (row < M) ? A[(size_t)row * K + k0 + c] : 0.f;
    }
    // B tile 32x64
    #pragma unroll
    for (int it = 0; it < (BK * BN) / 256; ++it) {
      int i = tid + it * 256;
      int r = i >> 6, c = i & 63;
      Bs[r][c] = B[(size_t)(k0 + r) * NC + bn + c];
    }
    __syncthreads();
    #pragma unroll
    for (int k = 0; k < BK; ++k) {
      float a[TM], b[TN];
      #pragma unroll
      for (int i = 0; i < TM; ++i) a[i] = As[k][tr * TM + i];
      #pragma unroll
      for (int j = 0; j < TN; ++j) b[j] = Bs[k][tc * TN + j];
      #pragma unroll
      for (int i = 0; i < TM; ++i)
        #pragma unroll
        for (int j = 0; j < TN; ++j)
          acc[i][j] += a[i] * b[j];
    }
    __syncthreads();
  }
  #pragma unroll
  for (int i = 0; i < TM; ++i) {
    int row = bm + tr * TM + i;
    if (row < M) {
      #pragma unroll
      for (int j = 0; j < TN; ++j)
        C[(size_t)row * NC + bn + tc * TN + j] = acc[i][j];
    }
  }
}

// ---------------------------------------------------------------------------
// Attention logit projections: asrc[n,h] = dot(H[n,h*D:(h+1)*D], a_src[h,:])
// One 64-lane group per (n,h); 4 groups per block.
// ---------------------------------------------------------------------------

__global__ __launch_bounds__(256) void alpha1_kernel(const float* __restrict__ H1,
                                                     const float* __restrict__ a_src,
                                                     const float* __restrict__ a_dst,
                                                     float* __restrict__ asrc,
                                                     float* __restrict__ adst, int N) {
  int g = blockIdx.x * 4 + (threadIdx.x >> 6);   // group id over N*HEADS
  int lane = threadIdx.x & 63;
  int n = g >> 2, h = g & 3;
  if (n >= N) return;
  float hv = H1[(size_t)n * C1 + h * HID + lane];
  float vs = hv * a_src[h * HID + lane];
  float vd = hv * a_dst[h * HID + lane];
  #pragma unroll
  for (int off = 32; off; off >>= 1) {
    vs += __shfl_xor(vs, off);
    vd += __shfl_xor(vd, off);
  }
  if (lane == 0) { asrc[n * HEADS + h] = vs; adst[n * HEADS + h] = vd; }
}

__global__ __launch_bounds__(256) void alpha2_kernel(const float* __restrict__ H2,
                                                     const float* __restrict__ a_src,
                                                     const float* __restrict__ a_dst,
                                                     float* __restrict__ asrc,
                                                     float* __restrict__ adst, int N) {
  int g = blockIdx.x * 4 + (threadIdx.x >> 6);   // node id
  int lane = threadIdx.x & 63;
  if (g >= N) return;
  float hv = H2[(size_t)g * HID + lane];
  float vs = hv * a_src[lane];
  float vd = hv * a_dst[lane];
  #pragma unroll
  for (int off = 32; off; off >>= 1) {
    vs += __shfl_xor(vs, off);
    vd += __shfl_xor(vd, off);
  }
  if (lane == 0) { asrc[g] = vs; adst[g] = vd; }
}

// ---------------------------------------------------------------------------
// GAT aggregation (layer 1): one block (256 thr = 256 feats) per dst node.
// Streaming two-pass segment softmax; fused bias + BN + ELU epilogue.
// ---------------------------------------------------------------------------

__global__ __launch_bounds__(256) void gat1_agg(const float* __restrict__ H1,
                                                const float* __restrict__ asrc,
                                                const float* __restrict__ adst,
                                                const int* __restrict__ indptr,
                                                const int* __restrict__ srcs,
                                                const float* __restrict__ b1,
                                                const float* __restrict__ g1,
                                                const float* __restrict__ be1,
                                                const float* __restrict__ mu1,
                                                const float* __restrict__ var1,
                                                float* __restrict__ X2, int N) {
  int n = blockIdx.x;
  int f = threadIdx.x;           // feature 0..255
  int h = f >> 6;                // head
  int start = indptr[n], end = indptr[n + 1];
  float ad = adst[n * HEADS + h];

  float m = -1e30f;
  for (int k = start; k < end; ++k) {
    int s = srcs[k];
    float e = asrc[s * HEADS + h] + ad;
    e = (e > 0.f) ? e : 0.2f * e;
    m = fmaxf(m, e);
  }
  float ssum = 0.f, acc = 0.f;
  for (int k = start; k < end; ++k) {
    int s = srcs[k];
    float e = asrc[s * HEADS + h] + ad;
    e = (e > 0.f) ? e : 0.2f * e;
    float p = __expf(e - m);
    ssum += p;
    acc += p * H1[(size_t)s * C1 + f];
  }
  float val = acc / (ssum + 1e-16f);
  val += b1[f];
  val = (val - mu1[f]) * (g1[f] * rsqrtf(var1[f] + 1e-5f)) + be1[f];
  val = (val > 0.f) ? val : (__expf(val) - 1.f);   // ELU
  X2[(size_t)n * C1 + f] = val;
}

// ---------------------------------------------------------------------------
// GAT aggregation (layer 2): one wave (64 feats) per dst node, 4 nodes/block.
// ---------------------------------------------------------------------------

__global__ __launch_bounds__(256) void gat2_agg(const float* __restrict__ H2,
                                                const float* __restrict__ asrc,
                                                const float* __restrict__ adst,
                                                const int* __restrict__ indptr,
                                                const int* __restrict__ srcs,
                                                const float* __restrict__ b2,
                                                const float* __restrict__ g2,
                                                const float* __restrict__ be2,
                                                const float* __restrict__ mu2,
                                                const float* __restrict__ var2,
                                                float* __restrict__ out, int N) {
  int n = blockIdx.x * 4 + (threadIdx.x >> 6);
  int lane = threadIdx.x & 63;
  if (n >= N) return;
  int start = indptr[n], end = indptr[n + 1];
  float ad = adst[n];

  float m = -1e30f;
  for (int k = start; k < end; ++k) {
    int s = srcs[k];
    float e = asrc[s] + ad;
    e = (e > 0.f) ? e : 0.2f * e;
    m = fmaxf(m, e);
  }
  float ssum = 0.f, acc = 0.f;
  for (int k = start; k < end; ++k) {
    int s = srcs[k];
    float e = asrc[s] + ad;
    e = (e > 0.f) ? e : 0.2f * e;
    float p = __expf(e - m);
    ssum += p;
    acc += p * H2[(size_t)s * HID + lane];
  }
  float val = acc / (ssum + 1e-16f);
  val += b2[lane];
  val = (val - mu2[lane]) * (g2[lane] * rsqrtf(var2[lane] + 1e-5f)) + be2[lane];
  val = (val > 0.f) ? val : (__expf(val) - 1.f);
  out[(size_t)n * HID + lane] = val;
}

// ---------------------------------------------------------------------------

extern "C" void kernel_launch(void* const* d_in, const int* in_sizes, int n_in,
                              void* d_out, int out_size, void* d_ws, size_t ws_size,
                              hipStream_t stream) {
  const float* x      = (const float*)d_in[0];
  const int*   ei     = (const int*)d_in[1];   // edge_index as int32 [2,E]
  const float* W1     = (const float*)d_in[2];
  const float* a_src1 = (const float*)d_in[3];
  const float* a_dst1 = (const float*)d_in[4];
  const float* b1     = (const float*)d_in[5];
  const float* g1     = (const float*)d_in[6];
  const float* be1    = (const float*)d_in[7];
  const float* mu1    = (const float*)d_in[8];
  const float* var1   = (const float*)d_in[9];
  const float* W2     = (const float*)d_in[10];
  const float* a_src2 = (const float*)d_in[11];
  const float* a_dst2 = (const float*)d_in[12];
  const float* b2     = (const float*)d_in[13];
  const float* g2     = (const float*)d_in[14];
  const float* be2    = (const float*)d_in[15];
  const float* mu2    = (const float*)d_in[16];
  const float* var2   = (const float*)d_in[17];
  float* out = (float*)d_out;

  int N = in_sizes[0] / IN_DIM;
  int E = in_sizes[1] / 2;
  int Etot = E + N;

  // Workspace layout (~108 MB):
  //   H1 [N*C1] | X2 [N*C1] | asrc1 [N*4] | adst1 [N*4] |
  //   indptr [N+1] | fillpos [N] | counts [N] | srcs [Etot]
  // Layer 2 reuses the H1 region for H2 [N*64] + asrc2 [N] + adst2 [N].
  float* fws   = (float*)d_ws;
  float* H1    = fws;
  float* X2    = H1 + (size_t)N * C1;
  float* asrc1 = X2 + (size_t)N * C1;
  float* adst1 = asrc1 + (size_t)N * HEADS;
  int* indptr  = (int*)(adst1 + (size_t)N * HEADS);
  int* fillpos = indptr + (N + 1);
  int* counts  = fillpos + N;
  int* srcs    = counts + N;
  float* H2    = H1;                        // reuse: H1 dead after gat1_agg
  float* asrc2 = H1 + (size_t)N * HID;
  float* adst2 = asrc2 + N;

  // --- CSR build (shared by both layers) ---
  zero_int_kernel<<<(N + 255) / 256, 256, 0, stream>>>(counts, N);
  hist_kernel<<<(Etot + 255) / 256, 256, 0, stream>>>(ei, E, N, counts);
  scan_kernel<<<1, 1024, 0, stream>>>(counts, indptr, fillpos, N);
  fill_kernel<<<(Etot + 255) / 256, 256, 0, stream>>>(ei, E, N, fillpos, srcs);

  // --- Layer 1 ---
  gemm_kernel<<<dim3((N + 63) / 64, C1 / 64), 256, 0, stream>>>(x, W1, H1, N, C1, IN_DIM);
  alpha1_kernel<<<N, 256, 0, stream>>>(H1, a_src1, a_dst1, asrc1, adst1, N);
  gat1_agg<<<N, 256, 0, stream>>>(H1, asrc1, adst1, indptr, srcs,
                                  b1, g1, be1, mu1, var1, X2, N);

  // --- Layer 2 ---
  gemm_kernel<<<dim3((N + 63) / 64, HID / 64), 256, 0, stream>>>(X2, W2, H2, N, HID, C1);
  alpha2_kernel<<<(N + 3) / 4, 256, 0, stream>>>(H2, a_src2, a_dst2, asrc2, adst2, N);
  gat2_agg<<<(N + 3) / 4, 256, 0, stream>>>(H2, asrc2, adst2, indptr, srcs,
                                            b2, g2, be2, mu2, var2, out, N);
}